// Round 2
// baseline (60.757 us; speedup 1.0000x reference)
//
#include <hip/hip_runtime.h>
#include <math.h>

// Problem constants (from reference setup_inputs)
#define BATCH 16
#define HIN   224
#define WIN   224
#define CCH   32
#define FDIM  128
#define HOUT  224
#define WOUT  224

#define PIX_PER_BATCH (HOUT * WOUT)          // 50176
#define THREADS_PER_PIX 8                    // 8 x float4 = 32 channels
#define BLOCK 256
#define PIX_PER_BLOCK (BLOCK / THREADS_PER_PIX)   // 32
#define BLOCKS_PER_BATCH (PIX_PER_BATCH / PIX_PER_BLOCK) // 1568
#define NBLOCKS (BATCH * BLOCKS_PER_BATCH)   // 25088
#define NXCD 8
#define BLOCKS_PER_XCD (NBLOCKS / NXCD)      // 3136 (exactly 2 batches)

// Fused kernel: per-block theta (6 length-128 dot products + tanh, identical
// sequential summation order to the reference GEMV) + bilinear sampling.
// One thread per (pixel, float4-of-channels): every global access is 16 B.
__global__ __launch_bounds__(BLOCK) void st_fused_kernel(
        const float* __restrict__ im,
        const float* __restrict__ tf,
        const float* __restrict__ Wm,
        const float* __restrict__ bv,
        float* __restrict__ out) {

    // --- chunked XCD swizzle: HW round-robins blockIdx across 8 XCDs;
    // remap so XCD k owns the contiguous block range [k*3136, (k+1)*3136)
    // = exactly 2 batches. Input-row reuse between consecutive output rows
    // then stays inside one XCD's L2 instead of bouncing through L3.
    int bid  = blockIdx.x;
    int nb   = (bid & (NXCD - 1)) * BLOCKS_PER_XCD + (bid >> 3);

    int bbatch = nb / BLOCKS_PER_BATCH;      // batch index of this block

    // --- theta for this batch, computed by 6 threads, broadcast via LDS
    __shared__ float th[6];
    if (threadIdx.x < 6) {
        int j = threadIdx.x;
        float acc = bv[j];
        const float* row = tf + bbatch * FDIM;
#pragma unroll 8
        for (int k = 0; k < FDIM; ++k) {
            acc += row[k] * Wm[k * 6 + j];
        }
        th[j] = tanhf(acc);
    }
    __syncthreads();

    float t0 = th[0], t1 = th[1], t2 = th[2];
    float t3 = th[3], t4 = th[4], t5 = th[5];

    int gid = nb * BLOCK + (int)threadIdx.x; // global work item
    int p   = gid >> 3;                      // output pixel index
    int c4  = gid & 7;                       // which float4 of 8 per pixel

    int rem = p - bbatch * PIX_PER_BATCH;
    int ho  = rem / WOUT;
    int wo  = rem - ho * WOUT;

    // linspace(-1,1,N): value i = -1 + 2*i/(N-1)
    float x_t = -1.0f + (2.0f * (float)wo) / (float)(WOUT - 1);
    float y_t = -1.0f + (2.0f * (float)ho) / (float)(HOUT - 1);

    float xs = t0 * x_t + t1 * y_t + t2;
    float ys = t3 * x_t + t4 * y_t + t5;

    float xp = (xs + 1.0f) * (0.5f * (float)WIN);
    float yp = (ys + 1.0f) * (0.5f * (float)HIN);

    float fx0 = floorf(xp);
    float fy0 = floorf(yp);
    int x0 = (int)fx0;
    int y0 = (int)fy0;
    int x1 = x0 + 1;
    int y1 = y0 + 1;

    // clip ints first; weights use the clipped coords (matches reference)
    x0 = min(max(x0, 0), WIN - 1);
    x1 = min(max(x1, 0), WIN - 1);
    y0 = min(max(y0, 0), HIN - 1);
    y1 = min(max(y1, 0), HIN - 1);

    float x0f = (float)x0, x1f = (float)x1;
    float y0f = (float)y0, y1f = (float)y1;

    float wa = (x1f - xp) * (y1f - yp);
    float wb = (x1f - xp) * (yp - y0f);
    float wc = (xp - x0f) * (y1f - yp);
    float wd = (xp - x0f) * (yp - y0f);

    const float4* imf4 = (const float4*)im;
    size_t base = (size_t)bbatch * (size_t)(HIN * WIN * 8);

    float4 Ia = imf4[base + ((size_t)(y0 * WIN + x0)) * 8 + c4];
    float4 Ib = imf4[base + ((size_t)(y1 * WIN + x0)) * 8 + c4];
    float4 Ic = imf4[base + ((size_t)(y0 * WIN + x1)) * 8 + c4];
    float4 Id = imf4[base + ((size_t)(y1 * WIN + x1)) * 8 + c4];

    float4 o;
    o.x = wa * Ia.x + wb * Ib.x + wc * Ic.x + wd * Id.x;
    o.y = wa * Ia.y + wb * Ib.y + wc * Ic.y + wd * Id.y;
    o.z = wa * Ia.z + wb * Ib.z + wc * Ic.z + wd * Id.z;
    o.w = wa * Ia.w + wb * Ib.w + wc * Ic.w + wd * Id.w;

    ((float4*)out)[gid] = o;
}

extern "C" void kernel_launch(void* const* d_in, const int* in_sizes, int n_in,
                              void* d_out, int out_size, void* d_ws, size_t ws_size,
                              hipStream_t stream) {
    const float* x  = (const float*)d_in[0];   // (16,224,224,32) f32
    const float* tf = (const float*)d_in[1];   // (16,128) f32
    const float* Wm = (const float*)d_in[2];   // (128,6) f32
    const float* bv = (const float*)d_in[3];   // (6,) f32
    float* out = (float*)d_out;                // (16,224,224,32) f32

    st_fused_kernel<<<NBLOCKS, BLOCK, 0, stream>>>(x, tf, Wm, bv, out);
}

// Round 3
// 36.399 us; speedup vs baseline: 1.6692x; 1.6692x over previous
//
#include <hip/hip_runtime.h>
#include <math.h>

// Problem constants (from reference setup_inputs)
#define BATCH 16
#define HIN   224
#define WIN   224
#define CCH   32
#define FDIM  128
#define HOUT  224
#define WOUT  224

#define PIX_PER_BATCH (HOUT * WOUT)               // 50176
#define BLOCK 256
#define PIX_PER_BLOCK (BLOCK / 8)                 // 32 pixels per block
#define BLOCKS_PER_BATCH (PIX_PER_BATCH / PIX_PER_BLOCK) // 1568
#define NBLOCKS (BATCH * BLOCKS_PER_BATCH)        // 25088
#define NXCD 8
#define BLOCKS_PER_XCD (NBLOCKS / NXCD)           // 3136 = exactly 2 batches

// ---------------- Kernel 1: theta = tanh(theta_feat @ W + b) ----------------
__global__ void st_theta_kernel(const float* __restrict__ tf,
                                const float* __restrict__ Wm,
                                const float* __restrict__ bv,
                                float* __restrict__ theta) {
    int t = blockIdx.x * blockDim.x + threadIdx.x;
    if (t >= BATCH * 6) return;
    int bi = t / 6;
    int j  = t - bi * 6;
    float acc = bv[j];
    const float* row = tf + bi * FDIM;
#pragma unroll 8
    for (int k = 0; k < FDIM; ++k) {
        acc += row[k] * Wm[k * 6 + j];
    }
    theta[t] = tanhf(acc);
}

// ---------------- Kernel 2: bilinear sampling ----------------
// One thread per (pixel, float4-of-channels). 8 threads per output pixel.
// XCD chunked swizzle: XCD k owns blocks [k*3136,(k+1)*3136) = 2 batches,
// so vertical input-row reuse stays in that XCD's 4MB L2.
__global__ __launch_bounds__(BLOCK) void st_sample_kernel(
        const float* __restrict__ im,
        const float* __restrict__ theta,
        float* __restrict__ out) {

    int bid = blockIdx.x;
    int nb  = (bid & (NXCD - 1)) * BLOCKS_PER_XCD + (bid >> 3);

    int gid = nb * BLOCK + (int)threadIdx.x;

    int p  = gid >> 3;        // pixel index
    int c4 = gid & 7;         // which float4 of the 8 per pixel

    int b   = p / PIX_PER_BATCH;
    int rem = p - b * PIX_PER_BATCH;
    int ho  = rem / WOUT;
    int wo  = rem - ho * WOUT;

    // linspace(-1,1,N): value i = -1 + 2*i/(N-1)
    float x_t = -1.0f + (2.0f * (float)wo) / (float)(WOUT - 1);
    float y_t = -1.0f + (2.0f * (float)ho) / (float)(HOUT - 1);

    const float* th = theta + b * 6;
    float t0 = th[0], t1 = th[1], t2 = th[2];
    float t3 = th[3], t4 = th[4], t5 = th[5];

    float xs = t0 * x_t + t1 * y_t + t2;
    float ys = t3 * x_t + t4 * y_t + t5;

    float xp = (xs + 1.0f) * (0.5f * (float)WIN);
    float yp = (ys + 1.0f) * (0.5f * (float)HIN);

    float fx0 = floorf(xp);
    float fy0 = floorf(yp);
    int x0 = (int)fx0;
    int y0 = (int)fy0;
    int x1 = x0 + 1;
    int y1 = y0 + 1;

    // clip ints first; weights use the clipped coords (matches reference)
    x0 = min(max(x0, 0), WIN - 1);
    x1 = min(max(x1, 0), WIN - 1);
    y0 = min(max(y0, 0), HIN - 1);
    y1 = min(max(y1, 0), HIN - 1);

    float x0f = (float)x0, x1f = (float)x1;
    float y0f = (float)y0, y1f = (float)y1;

    float wa = (x1f - xp) * (y1f - yp);
    float wb = (x1f - xp) * (yp - y0f);
    float wc = (xp - x0f) * (y1f - yp);
    float wd = (xp - x0f) * (yp - y0f);

    const float4* imf4 = (const float4*)im;
    size_t base = (size_t)b * (size_t)(HIN * WIN * 8);

    // compute all four addresses, then issue all four loads back-to-back
    // (independent -> 4 outstanding vmem ops per thread)
    size_t ia = base + ((size_t)(y0 * WIN + x0)) * 8 + c4;
    size_t ib = base + ((size_t)(y1 * WIN + x0)) * 8 + c4;
    size_t ic = base + ((size_t)(y0 * WIN + x1)) * 8 + c4;
    size_t id = base + ((size_t)(y1 * WIN + x1)) * 8 + c4;

    float4 Ia = imf4[ia];
    float4 Ib = imf4[ib];
    float4 Ic = imf4[ic];
    float4 Id = imf4[id];

    float4 o;
    o.x = wa * Ia.x + wb * Ib.x + wc * Ic.x + wd * Id.x;
    o.y = wa * Ia.y + wb * Ib.y + wc * Ic.y + wd * Id.y;
    o.z = wa * Ia.z + wb * Ib.z + wc * Ic.z + wd * Id.z;
    o.w = wa * Ia.w + wb * Ib.w + wc * Ic.w + wd * Id.w;

    ((float4*)out)[gid] = o;
}

extern "C" void kernel_launch(void* const* d_in, const int* in_sizes, int n_in,
                              void* d_out, int out_size, void* d_ws, size_t ws_size,
                              hipStream_t stream) {
    const float* x  = (const float*)d_in[0];   // (16,224,224,32) f32
    const float* tf = (const float*)d_in[1];   // (16,128) f32
    const float* Wm = (const float*)d_in[2];   // (128,6) f32
    const float* bv = (const float*)d_in[3];   // (6,) f32
    float* out = (float*)d_out;                // (16,224,224,32) f32

    float* theta = (float*)d_ws;               // 96 floats scratch

    st_theta_kernel<<<1, 128, 0, stream>>>(tf, Wm, bv, theta);
    st_sample_kernel<<<NBLOCKS, BLOCK, 0, stream>>>(x, theta, out);
}

// Round 4
// 33.828 us; speedup vs baseline: 1.7960x; 1.0760x over previous
//
#include <hip/hip_runtime.h>
#include <math.h>

// Problem constants (from reference setup_inputs)
#define BATCH 16
#define HIN   224
#define WIN   224
#define CCH   32
#define FDIM  128
#define HOUT  224
#define WOUT  224

#define PIX_PER_BATCH (HOUT * WOUT)               // 50176
#define BLOCK 256
#define ITEMS_PER_THREAD 2
#define ITEMS_PER_BLOCK (BLOCK * ITEMS_PER_THREAD)     // 512 items = 64 pixels
#define PIX_PER_BLOCK (ITEMS_PER_BLOCK / 8)            // 64
#define BLOCKS_PER_BATCH (PIX_PER_BATCH / PIX_PER_BLOCK) // 784
#define NBLOCKS (BATCH * BLOCKS_PER_BATCH)        // 12544
#define NXCD 8
#define BLOCKS_PER_XCD (NBLOCKS / NXCD)           // 1568 = exactly 2 batches

// ---------------- Kernel 1: theta = tanh(theta_feat @ W + b) ----------------
// One wave per (batch, j) output: 96 waves. 2 elements/lane + butterfly reduce.
__global__ void st_theta_kernel(const float* __restrict__ tf,
                                const float* __restrict__ Wm,
                                const float* __restrict__ bv,
                                float* __restrict__ theta) {
    int wid  = (int)((blockIdx.x * blockDim.x + threadIdx.x) >> 6);
    int lane = (int)(threadIdx.x & 63);
    if (wid >= BATCH * 6) return;
    int bi = wid / 6;
    int j  = wid - bi * 6;
    const float* row = tf + bi * FDIM;
    float acc = row[lane] * Wm[lane * 6 + j]
              + row[lane + 64] * Wm[(lane + 64) * 6 + j];
    acc += __shfl_xor(acc, 32);
    acc += __shfl_xor(acc, 16);
    acc += __shfl_xor(acc, 8);
    acc += __shfl_xor(acc, 4);
    acc += __shfl_xor(acc, 2);
    acc += __shfl_xor(acc, 1);
    if (lane == 0) theta[wid] = tanhf(acc + bv[j]);
}

// ---------------- Kernel 2: bilinear sampling ----------------
// Each thread handles TWO (pixel, float4-of-channels) items: base and
// base+256. 8 tap-loads + 2 stores in flight -> 2x memory-level parallelism.
// XCD chunked swizzle: XCD k owns 1568 consecutive blocks = exactly 2 batches,
// so vertical input-row reuse stays in that XCD's 4MB L2.
__global__ __launch_bounds__(BLOCK) void st_sample_kernel(
        const float* __restrict__ im,
        const float* __restrict__ theta,
        float* __restrict__ out) {

    int bid = blockIdx.x;
    int nb  = (bid & (NXCD - 1)) * BLOCKS_PER_XCD + (bid >> 3);

    int b = nb / BLOCKS_PER_BATCH;             // batch of this block

    // uniform theta for the batch (scalar-cached)
    const float* th = theta + b * 6;
    float t0 = th[0], t1 = th[1], t2 = th[2];
    float t3 = th[3], t4 = th[4], t5 = th[5];

    const float4* imf4 = (const float4*)im;
    float4* of4 = (float4*)out;
    size_t ibase = (size_t)b * (size_t)(HIN * WIN * 8);

    int base = nb * ITEMS_PER_BLOCK + (int)threadIdx.x;

    size_t addr[ITEMS_PER_THREAD][4];
    float  wgt[ITEMS_PER_THREAD][4];
    int    oidx[ITEMS_PER_THREAD];

#pragma unroll
    for (int u = 0; u < ITEMS_PER_THREAD; ++u) {
        int i  = base + u * BLOCK;             // global work item
        int p  = i >> 3;                       // output pixel
        int c4 = i & 7;                        // float4 chunk within pixel

        int rem = p - b * PIX_PER_BATCH;
        int ho  = rem / WOUT;
        int wo  = rem - ho * WOUT;

        float x_t = -1.0f + (2.0f * (float)wo) / (float)(WOUT - 1);
        float y_t = -1.0f + (2.0f * (float)ho) / (float)(HOUT - 1);

        float xs = t0 * x_t + t1 * y_t + t2;
        float ys = t3 * x_t + t4 * y_t + t5;

        float xp = (xs + 1.0f) * (0.5f * (float)WIN);
        float yp = (ys + 1.0f) * (0.5f * (float)HIN);

        int x0 = (int)floorf(xp);
        int y0 = (int)floorf(yp);
        int x1 = x0 + 1;
        int y1 = y0 + 1;

        x0 = min(max(x0, 0), WIN - 1);
        x1 = min(max(x1, 0), WIN - 1);
        y0 = min(max(y0, 0), HIN - 1);
        y1 = min(max(y1, 0), HIN - 1);

        float x0f = (float)x0, x1f = (float)x1;
        float y0f = (float)y0, y1f = (float)y1;

        wgt[u][0] = (x1f - xp) * (y1f - yp);   // wa
        wgt[u][1] = (x1f - xp) * (yp - y0f);   // wb
        wgt[u][2] = (xp - x0f) * (y1f - yp);   // wc
        wgt[u][3] = (xp - x0f) * (yp - y0f);   // wd

        addr[u][0] = ibase + ((size_t)(y0 * WIN + x0)) * 8 + c4;
        addr[u][1] = ibase + ((size_t)(y1 * WIN + x0)) * 8 + c4;
        addr[u][2] = ibase + ((size_t)(y0 * WIN + x1)) * 8 + c4;
        addr[u][3] = ibase + ((size_t)(y1 * WIN + x1)) * 8 + c4;
        oidx[u] = i;
    }

    // issue all 8 loads back-to-back (independent -> 8 outstanding vmem)
    float4 v[ITEMS_PER_THREAD][4];
#pragma unroll
    for (int u = 0; u < ITEMS_PER_THREAD; ++u) {
#pragma unroll
        for (int t = 0; t < 4; ++t) {
            v[u][t] = imf4[addr[u][t]];
        }
    }

#pragma unroll
    for (int u = 0; u < ITEMS_PER_THREAD; ++u) {
        float4 o;
        o.x = wgt[u][0] * v[u][0].x + wgt[u][1] * v[u][1].x
            + wgt[u][2] * v[u][2].x + wgt[u][3] * v[u][3].x;
        o.y = wgt[u][0] * v[u][0].y + wgt[u][1] * v[u][1].y
            + wgt[u][2] * v[u][2].y + wgt[u][3] * v[u][3].y;
        o.z = wgt[u][0] * v[u][0].z + wgt[u][1] * v[u][1].z
            + wgt[u][2] * v[u][2].z + wgt[u][3] * v[u][3].z;
        o.w = wgt[u][0] * v[u][0].w + wgt[u][1] * v[u][1].w
            + wgt[u][2] * v[u][2].w + wgt[u][3] * v[u][3].w;
        of4[oidx[u]] = o;
    }
}

extern "C" void kernel_launch(void* const* d_in, const int* in_sizes, int n_in,
                              void* d_out, int out_size, void* d_ws, size_t ws_size,
                              hipStream_t stream) {
    const float* x  = (const float*)d_in[0];   // (16,224,224,32) f32
    const float* tf = (const float*)d_in[1];   // (16,128) f32
    const float* Wm = (const float*)d_in[2];   // (128,6) f32
    const float* bv = (const float*)d_in[3];   // (6,) f32
    float* out = (float*)d_out;                // (16,224,224,32) f32

    float* theta = (float*)d_ws;               // 96 floats scratch

    st_theta_kernel<<<24, 256, 0, stream>>>(tf, Wm, bv, theta);
    st_sample_kernel<<<NBLOCKS, BLOCK, 0, stream>>>(x, theta, out);
}

// Round 5
// 33.336 us; speedup vs baseline: 1.8226x; 1.0148x over previous
//
#include <hip/hip_runtime.h>
#include <math.h>

// Problem constants (from reference setup_inputs)
#define BATCH 16
#define HIN   224
#define WIN   224
#define CCH   32
#define FDIM  128
#define HOUT  224
#define WOUT  224

#define PIX_PER_BATCH (HOUT * WOUT)               // 50176
#define BLOCK 256
#define ITEMS_PER_THREAD 4
#define ITEMS_PER_BLOCK (BLOCK * ITEMS_PER_THREAD)       // 1024 items = 128 pixels
#define PIX_PER_BLOCK (ITEMS_PER_BLOCK / 8)              // 128
#define BLOCKS_PER_BATCH (PIX_PER_BATCH / PIX_PER_BLOCK) // 392
#define NBLOCKS (BATCH * BLOCKS_PER_BATCH)        // 6272
#define NXCD 8
#define BLOCKS_PER_XCD (NBLOCKS / NXCD)           // 784 = exactly 2 batches

typedef float f32x4 __attribute__((ext_vector_type(4)));

// ---------------- Kernel 1: theta = tanh(theta_feat @ W + b) ----------------
// One wave per (batch, j) output: 96 waves. 2 elements/lane + butterfly reduce.
__global__ void st_theta_kernel(const float* __restrict__ tf,
                                const float* __restrict__ Wm,
                                const float* __restrict__ bv,
                                float* __restrict__ theta) {
    int wid  = (int)((blockIdx.x * blockDim.x + threadIdx.x) >> 6);
    int lane = (int)(threadIdx.x & 63);
    if (wid >= BATCH * 6) return;
    int bi = wid / 6;
    int j  = wid - bi * 6;
    const float* row = tf + bi * FDIM;
    float acc = row[lane] * Wm[lane * 6 + j]
              + row[lane + 64] * Wm[(lane + 64) * 6 + j];
    acc += __shfl_xor(acc, 32);
    acc += __shfl_xor(acc, 16);
    acc += __shfl_xor(acc, 8);
    acc += __shfl_xor(acc, 4);
    acc += __shfl_xor(acc, 2);
    acc += __shfl_xor(acc, 1);
    if (lane == 0) theta[wid] = tanhf(acc + bv[j]);
}

// ---------------- Kernel 2: bilinear sampling ----------------
// Each thread handles FOUR (pixel, float4-of-channels) items: 16 independent
// tap loads in flight per thread. Addresses kept as 32-bit float4-element
// offsets to cap VGPR pressure. Output written with nontemporal stores so the
// 100MB write stream doesn't evict the gather working set from L2.
// XCD chunked swizzle: XCD k owns 784 consecutive blocks = exactly 2 batches.
__global__ __launch_bounds__(BLOCK) void st_sample_kernel(
        const float* __restrict__ im,
        const float* __restrict__ theta,
        float* __restrict__ out) {

    int bid = blockIdx.x;
    int nb  = (bid & (NXCD - 1)) * BLOCKS_PER_XCD + (bid >> 3);

    int b = nb / BLOCKS_PER_BATCH;             // batch of this block

    // uniform theta for the batch (scalar-cached)
    const float* th = theta + b * 6;
    float t0 = th[0], t1 = th[1], t2 = th[2];
    float t3 = th[3], t4 = th[4], t5 = th[5];

    const f32x4* imf4 = (const f32x4*)im;
    f32x4* of4 = (f32x4*)out;
    unsigned ibase = (unsigned)b * (unsigned)(HIN * WIN * 8);

    int base = nb * ITEMS_PER_BLOCK + (int)threadIdx.x;

    unsigned addr[ITEMS_PER_THREAD][4];
    float    wgt[ITEMS_PER_THREAD][4];

#pragma unroll
    for (int u = 0; u < ITEMS_PER_THREAD; ++u) {
        int i  = base + u * BLOCK;             // global work item
        int p  = i >> 3;                       // output pixel
        int c4 = i & 7;                        // float4 chunk within pixel

        int rem = p - b * PIX_PER_BATCH;
        int ho  = rem / WOUT;
        int wo  = rem - ho * WOUT;

        float x_t = -1.0f + (2.0f * (float)wo) / (float)(WOUT - 1);
        float y_t = -1.0f + (2.0f * (float)ho) / (float)(HOUT - 1);

        float xs = t0 * x_t + t1 * y_t + t2;
        float ys = t3 * x_t + t4 * y_t + t5;

        float xp = (xs + 1.0f) * (0.5f * (float)WIN);
        float yp = (ys + 1.0f) * (0.5f * (float)HIN);

        int x0 = (int)floorf(xp);
        int y0 = (int)floorf(yp);
        int x1 = x0 + 1;
        int y1 = y0 + 1;

        x0 = min(max(x0, 0), WIN - 1);
        x1 = min(max(x1, 0), WIN - 1);
        y0 = min(max(y0, 0), HIN - 1);
        y1 = min(max(y1, 0), HIN - 1);

        float x0f = (float)x0, x1f = (float)x1;
        float y0f = (float)y0, y1f = (float)y1;

        wgt[u][0] = (x1f - xp) * (y1f - yp);   // wa
        wgt[u][1] = (x1f - xp) * (yp - y0f);   // wb
        wgt[u][2] = (xp - x0f) * (y1f - yp);   // wc
        wgt[u][3] = (xp - x0f) * (yp - y0f);   // wd

        addr[u][0] = ibase + (unsigned)(y0 * WIN + x0) * 8u + (unsigned)c4;
        addr[u][1] = ibase + (unsigned)(y1 * WIN + x0) * 8u + (unsigned)c4;
        addr[u][2] = ibase + (unsigned)(y0 * WIN + x1) * 8u + (unsigned)c4;
        addr[u][3] = ibase + (unsigned)(y1 * WIN + x1) * 8u + (unsigned)c4;
    }

    // issue all 16 loads back-to-back (independent -> 16 outstanding vmem)
    f32x4 v[ITEMS_PER_THREAD][4];
#pragma unroll
    for (int u = 0; u < ITEMS_PER_THREAD; ++u) {
#pragma unroll
        for (int t = 0; t < 4; ++t) {
            v[u][t] = imf4[addr[u][t]];
        }
    }

#pragma unroll
    for (int u = 0; u < ITEMS_PER_THREAD; ++u) {
        f32x4 o = wgt[u][0] * v[u][0] + wgt[u][1] * v[u][1]
                + wgt[u][2] * v[u][2] + wgt[u][3] * v[u][3];
        // nontemporal: output is write-only, keep L2 for gather taps
        __builtin_nontemporal_store(o, &of4[base + u * BLOCK]);
    }
}

extern "C" void kernel_launch(void* const* d_in, const int* in_sizes, int n_in,
                              void* d_out, int out_size, void* d_ws, size_t ws_size,
                              hipStream_t stream) {
    const float* x  = (const float*)d_in[0];   // (16,224,224,32) f32
    const float* tf = (const float*)d_in[1];   // (16,128) f32
    const float* Wm = (const float*)d_in[2];   // (128,6) f32
    const float* bv = (const float*)d_in[3];   // (6,) f32
    float* out = (float*)d_out;                // (16,224,224,32) f32

    float* theta = (float*)d_ws;               // 96 floats scratch

    st_theta_kernel<<<24, 256, 0, stream>>>(tf, Wm, bv, theta);
    st_sample_kernel<<<NBLOCKS, BLOCK, 0, stream>>>(x, theta, out);
}